// Round 8
// baseline (1304.433 us; speedup 1.0000x reference)
//
#include <hip/hip_runtime.h>
#include <hip/hip_bf16.h>
#include <math.h>

#define NN 100000
#define EE 400000
#define KD 2
#define DD 256
#define ATTD 64
#define LL 3
#define HH1 128
#define HH2 64
#define EPSV 1e-5f
#define SLOPE 0.01f
#define KN (KD * NN)

typedef short short8 __attribute__((ext_vector_type(8)));
typedef float floatx4 __attribute__((ext_vector_type(4)));
typedef unsigned short u16;
typedef unsigned int u32;

__device__ __forceinline__ u16 f2bf(float f) {
    u32 u = __float_as_uint(f);
    return (u16)((u + 0x7fffu + ((u >> 16) & 1u)) >> 16);
}
__device__ __forceinline__ float bf2f(u16 h) {
    return __uint_as_float((u32)h << 16);
}

// ---------------- BatchNorm ----------------
__global__ void bn_stats(const float* __restrict__ x, float* __restrict__ sums) {
    int d = threadIdx.x;
    int r0 = blockIdx.x * 125;
    float s = 0.f, sq = 0.f;
    for (int r = r0; r < r0 + 125; ++r) {
        float v = x[(size_t)r * DD + d];
        s += v; sq += v * v;
    }
    atomicAdd(&sums[d], s);
    atomicAdd(&sums[DD + d], sq);
}

// writes h as pre-split bf16 hi/lo planes (numerically = runtime split in GEMM)
__global__ void bn_apply(const float* __restrict__ x, const float* __restrict__ sums,
                         const float* __restrict__ gamma, const float* __restrict__ beta,
                         u16* __restrict__ h_hi, u16* __restrict__ h_lo) {
    size_t i = (size_t)blockIdx.x * blockDim.x + threadIdx.x;
    const float inv_n = 1.f / NN;
    int dq = (int)(i & 63) * 4;
    float4 xv = ((const float4*)x)[i];
    ushort4 hv, lv;
    float* xp = (float*)&xv;
    u16* hp = (u16*)&hv; u16* lp = (u16*)&lv;
#pragma unroll
    for (int j = 0; j < 4; ++j) {
        int d = dq + j;
        float mu = sums[d] * inv_n;
        float var = sums[DD + d] * inv_n - mu * mu;
        float inv = rsqrtf(var + EPSV);
        float v = (xp[j] - mu) * inv * gamma[d] + beta[d];
        u16 hb = f2bf(v);
        hp[j] = hb;
        lp[j] = f2bf(v - bf2f(hb));
    }
    ((ushort4*)h_hi)[i] = hv;
    ((ushort4*)h_lo)[i] = lv;
}

// ---------------- degree ----------------
__global__ void deg_accum(const int* __restrict__ ei, const float* __restrict__ w,
                          float* __restrict__ deg) {
    int i = blockIdx.x * blockDim.x + threadIdx.x;
    if (i >= KD * EE) return;
    int k = i / EE, e = i - k * EE;
    int col = ei[(size_t)k * 2 * EE + EE + e];
    atomicAdd(&deg[k * NN + col], w[i]);
}

__global__ void dinv_kernel(float* __restrict__ d) {
    int i = blockIdx.x * blockDim.x + threadIdx.x;
    if (i >= KD * NN) return;
    float v = d[i];
    d[i] = v > 0.f ? 1.f / sqrtf(v) : 0.f;
}

// ---------------- CSR build ----------------
__global__ void csr_count(const int* __restrict__ ei, int* __restrict__ starts) {
    int i = blockIdx.x * blockDim.x + threadIdx.x;
    if (i >= KD * EE) return;
    int k = i / EE, e = i - k * EE;
    int col = ei[(size_t)k * 2 * EE + EE + e];
    atomicAdd(&starts[k * NN + col], 1);
}

#define SCAN_NB ((KN + 255) / 256)   // 782
__global__ void scan_blocks(int* __restrict__ starts, int* __restrict__ bsums) {
    __shared__ int tmp[256];
    int t = threadIdx.x;
    int idx = blockIdx.x * 256 + t;
    int v = (idx < KN) ? starts[idx] : 0;
    tmp[t] = v;
    __syncthreads();
#pragma unroll
    for (int off = 1; off < 256; off <<= 1) {
        int s = (t >= off) ? tmp[t - off] : 0;
        __syncthreads();
        tmp[t] += s;
        __syncthreads();
    }
    if (idx < KN) starts[idx] = tmp[t] - v;          // exclusive
    if (t == 255) bsums[blockIdx.x] = tmp[255];      // block total
}

__global__ void scan_sums(int* __restrict__ bsums) {
    __shared__ int tmp[1024];
    int t = threadIdx.x;
    int v = (t < SCAN_NB) ? bsums[t] : 0;
    tmp[t] = v;
    __syncthreads();
#pragma unroll
    for (int off = 1; off < 1024; off <<= 1) {
        int s = (t >= off) ? tmp[t - off] : 0;
        __syncthreads();
        tmp[t] += s;
        __syncthreads();
    }
    if (t < SCAN_NB) bsums[t] = tmp[t] - v;          // exclusive
}

__global__ void scan_add(int* __restrict__ starts, const int* __restrict__ bsums) {
    int idx = blockIdx.x * 256 + threadIdx.x;
    if (idx < KN) starts[idx] += bsums[blockIdx.x];
}

__global__ void csr_fill(const int* __restrict__ ei, const float* __restrict__ w,
                         const float* __restrict__ dinv,
                         int* __restrict__ starts, int2* __restrict__ edata) {
    int i = blockIdx.x * blockDim.x + threadIdx.x;
    if (i >= KD * EE) return;
    int k = i / EE, e = i - k * EE;
    const int* eik = ei + (size_t)k * 2 * EE;
    int row = eik[e], col = eik[EE + e];
    float nv = dinv[k * NN + col] * w[i] * dinv[k * NN + row];
    int pos = atomicAdd(&starts[k * NN + col], 1);
    edata[pos] = make_int2(row, __float_as_int(nv));
}

// ---------------- gather aggregation: xs(bf16)[widx,:] = sum_e norm_e * xw[row_e,:] ----------------
__global__ __launch_bounds__(256) void gather_agg(
        const int* __restrict__ starts, const int2* __restrict__ edata,
        const __hip_bfloat16* __restrict__ xw, u16* __restrict__ xs) {
    int widx = blockIdx.x * 4 + (threadIdx.x >> 6);
    if (widx >= KN) return;
    int lane = threadIdx.x & 63;
    int begin = widx ? starts[widx - 1] : 0;
    int end = starts[widx];
    float4 acc = make_float4(0.f, 0.f, 0.f, 0.f);
    for (int e = begin; e < end; ++e) {
        int2 ed = edata[e];
        float nv = __int_as_float(ed.y);
        const __hip_bfloat162* p =
            (const __hip_bfloat162*)(xw + (size_t)ed.x * DD + lane * 4);
        float2 f0 = __bfloat1622float2(p[0]);
        float2 f1 = __bfloat1622float2(p[1]);
        acc.x += nv * f0.x; acc.y += nv * f0.y;
        acc.z += nv * f1.x; acc.w += nv * f1.y;
    }
    ushort4 st = make_ushort4(f2bf(acc.x), f2bf(acc.y), f2bf(acc.z), f2bf(acc.w));
    *(ushort4*)(xs + (size_t)widx * DD + lane * 4) = st;
}

// ---------------- weight convert + transpose: Wt[n][k] = bf16(W[k][n]) ----------------
__global__ void wconv(const float* __restrict__ W, u16* __restrict__ Wt, int Kd, int Nc) {
    int i = blockIdx.x * 256 + threadIdx.x;
    if (i >= Kd * Nc) return;
    int kk = i / Nc, n = i - kk * Nc;
    Wt[(size_t)n * Kd + kk] = f2bf(W[i]);
}

// ---------------- fold gcn_b into attention bias ----------------
__global__ void att_bias_fold(const float* __restrict__ attW, const float* __restrict__ attb,
                              const float* __restrict__ gcnb, float* __restrict__ batt) {
    int lk = blockIdx.x;          // 0..5
    int a = threadIdx.x;          // 0..63
    int l = lk >> 1;
    const float* W = attW + (size_t)lk * DD * ATTD;
    const float* gb = gcnb + l * DD;
    float s = attb[lk * ATTD + a];
    for (int d = 0; d < DD; ++d) s += gb[d] * W[d * ATTD + a];
    batt[lk * ATTD + a] = s;
}

#define LDSP 40   // LDS row stride in u16 (32 + 8 pad)

// ---------------- MFMA GEMM ----------------
// C(M x Nc) = A @ B, B pre-transposed bf16 Bt[n][k].
// PRESPLIT: A given as pre-split bf16 hi/lo planes (pure-copy staging).
// else: A fp32, runtime hi/lo split in staging.
// MODE 0: store fp32 C (opt bias/act). MODE 1: store bf16 Cb.
template<int BN_, int MODE, bool PRESPLIT, bool BIAS, int ACT>
__global__ __launch_bounds__(256) void gemm_mfma(
        const float* __restrict__ A,
        const u16* __restrict__ Ahi, const u16* __restrict__ Alo,
        const u16* __restrict__ Bt, const float* __restrict__ bias,
        float* __restrict__ Cf, u16* __restrict__ Cb,
        int M, int Kd, int Nc) {
    constexpr int JW = BN_ / 32;
    __shared__ u16 AsHi[128 * LDSP];
    __shared__ u16 AsLo[128 * LDSP];
    __shared__ u16 Bs[BN_ * LDSP];

    const int tid = threadIdx.x;
    const int lane = tid & 63, waveid = tid >> 6;
    const int wy = waveid >> 1, wx = waveid & 1;
    const int lane15 = lane & 15, quad = lane >> 4;
    const int bm = blockIdx.x * 128;
    const int bn = blockIdx.y * BN_;

    floatx4 acc[4][JW];
#pragma unroll
    for (int i = 0; i < 4; ++i)
#pragma unroll
        for (int j = 0; j < JW; ++j) acc[i][j] = (floatx4){0.f, 0.f, 0.f, 0.f};

    for (int k0 = 0; k0 < Kd; k0 += 32) {
        if constexpr (PRESPLIT) {
#pragma unroll
            for (int t = tid; t < 512; t += 256) {
                int m = t >> 2, ko = (t & 3) << 3;
                uint4 vh = make_uint4(0, 0, 0, 0), vl = make_uint4(0, 0, 0, 0);
                if (bm + m < M) {
                    vh = *(const uint4*)(Ahi + (size_t)(bm + m) * Kd + k0 + ko);
                    vl = *(const uint4*)(Alo + (size_t)(bm + m) * Kd + k0 + ko);
                }
                *(uint4*)(void*)(AsHi + m * LDSP + ko) = vh;
                *(uint4*)(void*)(AsLo + m * LDSP + ko) = vl;
            }
        } else {
#pragma unroll
            for (int t = tid; t < 1024; t += 256) {
                int m = t >> 3, k4 = (t & 7) << 2;
                float4 v = make_float4(0.f, 0.f, 0.f, 0.f);
                if (bm + m < M) v = *(const float4*)(A + (size_t)(bm + m) * Kd + k0 + k4);
                u16 h0 = f2bf(v.x), h1 = f2bf(v.y), h2 = f2bf(v.z), h3 = f2bf(v.w);
                *(ushort4*)(void*)(AsHi + m * LDSP + k4) = make_ushort4(h0, h1, h2, h3);
                u16 l0 = f2bf(v.x - bf2f(h0)), l1 = f2bf(v.y - bf2f(h1));
                u16 l2 = f2bf(v.z - bf2f(h2)), l3 = f2bf(v.w - bf2f(h3));
                *(ushort4*)(void*)(AsLo + m * LDSP + k4) = make_ushort4(l0, l1, l2, l3);
            }
        }
#pragma unroll
        for (int t = tid; t < BN_ * 4; t += 256) {
            int n = t >> 2, ko = (t & 3) << 3;
            uint4 w = *(const uint4*)(Bt + (size_t)(bn + n) * Kd + k0 + ko);
            *(uint4*)(void*)(Bs + n * LDSP + ko) = w;
        }
        __syncthreads();

        const u16* pA  = AsHi + (wy * 64 + lane15) * LDSP + quad * 8;
        const u16* pAl = AsLo + (wy * 64 + lane15) * LDSP + quad * 8;
        const u16* pB  = Bs + (wx * (BN_ / 2) + lane15) * LDSP + quad * 8;
        short8 b[JW];
#pragma unroll
        for (int j = 0; j < JW; ++j) b[j] = *(const short8*)(pB + j * 16 * LDSP);
#pragma unroll
        for (int i = 0; i < 4; ++i) {
            short8 a = *(const short8*)(pA + i * 16 * LDSP);
#pragma unroll
            for (int j = 0; j < JW; ++j)
                acc[i][j] = __builtin_amdgcn_mfma_f32_16x16x32_bf16(a, b[j], acc[i][j], 0, 0, 0);
        }
#pragma unroll
        for (int i = 0; i < 4; ++i) {
            short8 a = *(const short8*)(pAl + i * 16 * LDSP);
#pragma unroll
            for (int j = 0; j < JW; ++j)
                acc[i][j] = __builtin_amdgcn_mfma_f32_16x16x32_bf16(a, b[j], acc[i][j], 0, 0, 0);
        }
        __syncthreads();
    }

#pragma unroll
    for (int i = 0; i < 4; ++i) {
#pragma unroll
        for (int r = 0; r < 4; ++r) {
            int row = bm + wy * 64 + i * 16 + quad * 4 + r;
            if (row >= M) continue;
#pragma unroll
            for (int j = 0; j < JW; ++j) {
                int col = bn + wx * (BN_ / 2) + j * 16 + lane15;
                float v = acc[i][j][r];
                if constexpr (BIAS) v += bias[col];
                if constexpr (ACT == 1) v = v > 0.f ? v : SLOPE * v;
                if constexpr (MODE == 0) Cf[(size_t)row * Nc + col] = v;
                else                     Cb[(size_t)row * Nc + col] = f2bf(v);
            }
        }
    }
}

// ---------------- fused attention: keys/tanh/sim both k, softmax, combine, relu ----------------
// writes h as pre-split bf16 hi/lo planes
__global__ __launch_bounds__(256) void att_combine(
        const u16* __restrict__ xs, const u16* __restrict__ Bt,
        const float* __restrict__ batt, const float* __restrict__ qv,
        const float* __restrict__ gcnb,
        u16* __restrict__ h_hi, u16* __restrict__ h_lo) {
    __shared__ u16 As[KD][128 * LDSP];
    __shared__ u16 Bs[KD][ATTD * LDSP];
    __shared__ float simbuf[KD][4][64];

    const int tid = threadIdx.x;
    const int lane = tid & 63, waveid = tid >> 6;
    const int wy = waveid >> 1, wx = waveid & 1;
    const int lane15 = lane & 15, quad = lane >> 4;
    const int bm = blockIdx.x * 128;

    floatx4 acc[KD][4][2];
#pragma unroll
    for (int k = 0; k < KD; ++k)
#pragma unroll
        for (int i = 0; i < 4; ++i)
#pragma unroll
            for (int j = 0; j < 2; ++j) acc[k][i][j] = (floatx4){0.f, 0.f, 0.f, 0.f};

    for (int k0 = 0; k0 < DD; k0 += 32) {
#pragma unroll
        for (int k = 0; k < KD; ++k) {
#pragma unroll
            for (int t = tid; t < 512; t += 256) {
                int m = t >> 2, ko = (t & 3) << 3;
                uint4 v = make_uint4(0, 0, 0, 0);
                if (bm + m < NN)
                    v = *(const uint4*)(xs + ((size_t)k * NN + bm + m) * DD + k0 + ko);
                *(uint4*)(void*)(As[k] + m * LDSP + ko) = v;
            }
            {
                int n = tid >> 2, ko = (tid & 3) << 3;
                uint4 w = *(const uint4*)(Bt + (size_t)k * ATTD * DD + (size_t)n * DD + k0 + ko);
                *(uint4*)(void*)(Bs[k] + n * LDSP + ko) = w;
            }
        }
        __syncthreads();
#pragma unroll
        for (int k = 0; k < KD; ++k) {
            const u16* pA = As[k] + (wy * 64 + lane15) * LDSP + quad * 8;
            const u16* pB = Bs[k] + (wx * 32 + lane15) * LDSP + quad * 8;
            short8 b[2];
            b[0] = *(const short8*)(pB);
            b[1] = *(const short8*)(pB + 16 * LDSP);
#pragma unroll
            for (int i = 0; i < 4; ++i) {
                short8 a = *(const short8*)(pA + i * 16 * LDSP);
                acc[k][i][0] = __builtin_amdgcn_mfma_f32_16x16x32_bf16(a, b[0], acc[k][i][0], 0, 0, 0);
                acc[k][i][1] = __builtin_amdgcn_mfma_f32_16x16x32_bf16(a, b[1], acc[k][i][1], 0, 0, 0);
            }
        }
        __syncthreads();
    }

#pragma unroll
    for (int k = 0; k < KD; ++k) {
#pragma unroll
        for (int i = 0; i < 4; ++i) {
#pragma unroll
            for (int r = 0; r < 4; ++r) {
                float p = 0.f;
#pragma unroll
                for (int j = 0; j < 2; ++j) {
                    int col = wx * 32 + j * 16 + lane15;
                    float v = acc[k][i][j][r] + batt[k * ATTD + col];
                    p += tanhf(v) * qv[k * ATTD + col];
                }
                p += __shfl_xor(p, 1, 64);
                p += __shfl_xor(p, 2, 64);
                p += __shfl_xor(p, 4, 64);
                p += __shfl_xor(p, 8, 64);
                if (lane15 == 0) simbuf[k][wy * 2 + wx][i * 16 + quad * 4 + r] = p;
            }
        }
    }
    __syncthreads();

#pragma unroll 4
    for (int it = 0; it < 32; ++it) {
        int item = tid + it * 256;
        int row = item >> 6, dq = item & 63;
        int grow = bm + row;
        if (grow >= NN) continue;
        int wy2 = row >> 6, rl = row & 63;
        float s0 = simbuf[0][wy2 * 2 + 0][rl] + simbuf[0][wy2 * 2 + 1][rl];
        float s1 = simbuf[1][wy2 * 2 + 0][rl] + simbuf[1][wy2 * 2 + 1][rl];
        float m = fmaxf(s0, s1);
        float e0 = __expf(s0 - m), e1 = __expf(s1 - m);
        float inv = 1.f / (e0 + e1);
        float a0 = e0 * inv, a1 = e1 * inv;
        const __hip_bfloat162* p0 = (const __hip_bfloat162*)(xs + (size_t)grow * DD + dq * 4);
        const __hip_bfloat162* p1 = (const __hip_bfloat162*)(xs + ((size_t)NN + grow) * DD + dq * 4);
        float2 v00 = __bfloat1622float2(p0[0]), v01 = __bfloat1622float2(p0[1]);
        float2 v10 = __bfloat1622float2(p1[0]), v11 = __bfloat1622float2(p1[1]);
        float4 bv = ((const float4*)gcnb)[dq];
        float r0 = fmaxf(0.f, a0 * v00.x + a1 * v10.x + bv.x);
        float r1 = fmaxf(0.f, a0 * v00.y + a1 * v10.y + bv.y);
        float r2 = fmaxf(0.f, a0 * v01.x + a1 * v11.x + bv.z);
        float r3 = fmaxf(0.f, a0 * v01.y + a1 * v11.y + bv.w);
        u16 hb0 = f2bf(r0), hb1 = f2bf(r1), hb2 = f2bf(r2), hb3 = f2bf(r3);
        *(ushort4*)(h_hi + (size_t)grow * DD + dq * 4) = make_ushort4(hb0, hb1, hb2, hb3);
        *(ushort4*)(h_lo + (size_t)grow * DD + dq * 4) =
            make_ushort4(f2bf(r0 - bf2f(hb0)), f2bf(r1 - bf2f(hb1)),
                         f2bf(r2 - bf2f(hb2)), f2bf(r3 - bf2f(hb3)));
    }
}

extern "C" void kernel_launch(void* const* d_in, const int* in_sizes, int n_in,
                              void* d_out, int out_size, void* d_ws, size_t ws_size,
                              hipStream_t stream) {
    const float* x     = (const float*)d_in[0];
    const int*   ei    = (const int*)d_in[1];
    const float* ew    = (const float*)d_in[2];
    const float* gamma = (const float*)d_in[3];
    const float* beta  = (const float*)d_in[4];
    const float* gcn_W = (const float*)d_in[5];
    const float* gcn_b = (const float*)d_in[6];
    const float* att_W = (const float*)d_in[7];
    const float* att_b = (const float*)d_in[8];
    const float* att_q = (const float*)d_in[9];
    const float* pW1   = (const float*)d_in[10];
    const float* pb1   = (const float*)d_in[11];
    const float* pW2   = (const float*)d_in[12];
    const float* pb2   = (const float*)d_in[13];
    float* out = (float*)d_out;

    char* wsb = (char*)d_ws;
    size_t off = 0;
    auto alloc = [&](size_t bytes) -> void* {
        void* p = wsb + off;
        off += (bytes + 255) & ~(size_t)255;
        return p;
    };
    u16*   xs    = (u16*)alloc((size_t)KD * NN * DD * 2);     // 102.4 MB (bf16)
    u16*   h_hi  = (u16*)alloc((size_t)NN * DD * 2);          // 51.2 MB
    u16*   h_lo  = (u16*)alloc((size_t)NN * DD * 2);          // 51.2 MB
    u16*   xw    = (u16*)alloc((size_t)NN * DD * 2);          // 51.2 MB
    float* p1tmp = (float*)xw;                                // N*H1*4, exact reuse
    float* dinv  = (float*)alloc((size_t)KN * 4);
    int*   starts= (int*)alloc(((size_t)KN + 1) * 4);
    int2*  edata = (int2*)alloc((size_t)KD * EE * 8);         // 6.4 MB
    float* bnsums= (float*)alloc(2 * DD * 4);
    u16*   gcnWb = (u16*)alloc((size_t)LL * DD * DD * 2);
    u16*   attWb = (u16*)alloc((size_t)LL * KD * ATTD * DD * 2);
    u16*   pW1b  = (u16*)alloc((size_t)HH1 * DD * 2);
    u16*   pW2b  = (u16*)alloc((size_t)HH2 * HH1 * 2);
    float* batt  = (float*)alloc((size_t)LL * KD * ATTD * 4);
    int*   bsums = (int*)alloc((size_t)SCAN_NB * 4);

    // ---- setup: weight transpose/convert + att bias fold ----
    for (int l = 0; l < LL; ++l)
        wconv<<<(DD * DD + 255) / 256, 256, 0, stream>>>(gcn_W + (size_t)l * DD * DD,
                                                         gcnWb + (size_t)l * DD * DD, DD, DD);
    for (int lk = 0; lk < LL * KD; ++lk)
        wconv<<<(DD * ATTD + 255) / 256, 256, 0, stream>>>(att_W + (size_t)lk * DD * ATTD,
                                                           attWb + (size_t)lk * ATTD * DD, DD, ATTD);
    wconv<<<(DD * HH1 + 255) / 256, 256, 0, stream>>>(pW1, pW1b, DD, HH1);
    wconv<<<(HH1 * HH2 + 255) / 256, 256, 0, stream>>>(pW2, pW2b, HH1, HH2);
    att_bias_fold<<<LL * KD, ATTD, 0, stream>>>(att_W, att_b, gcn_b, batt);

    // ---- BatchNorm -> h (pre-split) ----
    hipMemsetAsync(bnsums, 0, 2 * DD * 4, stream);
    bn_stats<<<800, 256, 0, stream>>>(x, bnsums);
    bn_apply<<<25000, 256, 0, stream>>>(x, bnsums, gamma, beta, h_hi, h_lo);

    // ---- degree / dinv / CSR (layer-invariant) ----
    hipMemsetAsync(dinv, 0, (size_t)KN * 4, stream);
    deg_accum<<<(KD * EE + 255) / 256, 256, 0, stream>>>(ei, ew, dinv);
    dinv_kernel<<<(KN + 255) / 256, 256, 0, stream>>>(dinv);
    hipMemsetAsync(starts, 0, ((size_t)KN + 1) * 4, stream);
    csr_count<<<(KD * EE + 255) / 256, 256, 0, stream>>>(ei, starts);
    scan_blocks<<<SCAN_NB, 256, 0, stream>>>(starts, bsums);
    scan_sums<<<1, 1024, 0, stream>>>(bsums);
    scan_add<<<SCAN_NB, 256, 0, stream>>>(starts, bsums);
    csr_fill<<<(KD * EE + 255) / 256, 256, 0, stream>>>(ei, ew, dinv, starts, edata);

    const int MB = (NN + 127) / 128;   // 782
    for (int l = 0; l < LL; ++l) {
        // xw(bf16) = h @ gcn_W[l]  — full-width 128x256 tile, pure-copy staging
        gemm_mfma<256, 1, true, false, 0><<<dim3(MB, 1), 256, 0, stream>>>(
            nullptr, h_hi, h_lo, gcnWb + (size_t)l * DD * DD, nullptr,
            nullptr, xw, NN, DD, DD);
        gather_agg<<<(KN + 3) / 4, 256, 0, stream>>>(starts, edata,
                                                     (const __hip_bfloat16*)xw, xs);
        att_combine<<<MB, 256, 0, stream>>>(
            xs, attWb + (size_t)l * KD * ATTD * DD,
            batt + (size_t)l * KD * ATTD, att_q + (size_t)l * KD * ATTD,
            gcn_b + l * DD, h_hi, h_lo);
    }

    // ---- projection head ----
    gemm_mfma<128, 0, true, true, 1><<<dim3(MB, 1), 256, 0, stream>>>(
        nullptr, h_hi, h_lo, pW1b, pb1, p1tmp, nullptr, NN, DD, HH1);
    gemm_mfma<64, 0, false, true, 1><<<dim3(MB, 1), 256, 0, stream>>>(
        p1tmp, nullptr, nullptr, pW2b, pb2, out, nullptr, NN, HH1, HH2);
}

// Round 10
// 1105.266 us; speedup vs baseline: 1.1802x; 1.1802x over previous
//
#include <hip/hip_runtime.h>
#include <hip/hip_bf16.h>
#include <math.h>

#define NN 100000
#define EE 400000
#define KD 2
#define DD 256
#define ATTD 64
#define LL 3
#define HH1 128
#define HH2 64
#define EPSV 1e-5f
#define SLOPE 0.01f
#define KN (KD * NN)

typedef short short8 __attribute__((ext_vector_type(8)));
typedef float floatx4 __attribute__((ext_vector_type(4)));
typedef unsigned short u16;
typedef unsigned int u32;
typedef unsigned long long u64;

__device__ __forceinline__ u16 f2bf(float f) {
    u32 u = __float_as_uint(f);
    return (u16)((u + 0x7fffu + ((u >> 16) & 1u)) >> 16);
}
__device__ __forceinline__ float bf2f(u16 h) {
    return __uint_as_float((u32)h << 16);
}

// ---------------- BatchNorm ----------------
__global__ void bn_stats(const float* __restrict__ x, float* __restrict__ sums) {
    int d = threadIdx.x;
    int r0 = blockIdx.x * 125;
    float s = 0.f, sq = 0.f;
    for (int r = r0; r < r0 + 125; ++r) {
        float v = x[(size_t)r * DD + d];
        s += v; sq += v * v;
    }
    atomicAdd(&sums[d], s);
    atomicAdd(&sums[DD + d], sq);
}

// writes h as pre-split bf16 hi/lo planes
__global__ void bn_apply(const float* __restrict__ x, const float* __restrict__ sums,
                         const float* __restrict__ gamma, const float* __restrict__ beta,
                         u16* __restrict__ h_hi, u16* __restrict__ h_lo) {
    size_t i = (size_t)blockIdx.x * blockDim.x + threadIdx.x;
    const float inv_n = 1.f / NN;
    int dq = (int)(i & 63) * 4;
    float4 xv = ((const float4*)x)[i];
    ushort4 hv, lv;
    float* xp = (float*)&xv;
    u16* hp = (u16*)&hv; u16* lp = (u16*)&lv;
#pragma unroll
    for (int j = 0; j < 4; ++j) {
        int d = dq + j;
        float mu = sums[d] * inv_n;
        float var = sums[DD + d] * inv_n - mu * mu;
        float inv = rsqrtf(var + EPSV);
        float v = (xp[j] - mu) * inv * gamma[d] + beta[d];
        u16 hb = f2bf(v);
        hp[j] = hb;
        lp[j] = f2bf(v - bf2f(hb));
    }
    ((ushort4*)h_hi)[i] = hv;
    ((ushort4*)h_lo)[i] = lv;
}

// ---------------- degree + CSR count (merged) ----------------
__global__ void deg_count(const int* __restrict__ ei, const float* __restrict__ w,
                          float* __restrict__ deg, int* __restrict__ counts) {
    int i = blockIdx.x * blockDim.x + threadIdx.x;
    if (i >= KD * EE) return;
    int k = i / EE, e = i - k * EE;
    int col = ei[(size_t)k * 2 * EE + EE + e];
    atomicAdd(&deg[k * NN + col], w[i]);
    atomicAdd(&counts[k * NN + col], 1);
}

__global__ void dinv_kernel(float* __restrict__ d) {
    int i = blockIdx.x * blockDim.x + threadIdx.x;
    if (i >= KD * NN) return;
    float v = d[i];
    d[i] = v > 0.f ? 1.f / sqrtf(v) : 0.f;
}

#define SCAN_NB ((KN + 255) / 256)   // 782
__global__ void scan_blocks(int* __restrict__ starts, int* __restrict__ bsums) {
    __shared__ int tmp[256];
    int t = threadIdx.x;
    int idx = blockIdx.x * 256 + t;
    int v = (idx < KN) ? starts[idx] : 0;
    tmp[t] = v;
    __syncthreads();
#pragma unroll
    for (int off = 1; off < 256; off <<= 1) {
        int s = (t >= off) ? tmp[t - off] : 0;
        __syncthreads();
        tmp[t] += s;
        __syncthreads();
    }
    if (idx < KN) starts[idx] = tmp[t] - v;          // exclusive
    if (t == 255) bsums[blockIdx.x] = tmp[255];      // block total
}

__global__ void scan_sums(int* __restrict__ bsums) {
    __shared__ int tmp[1024];
    int t = threadIdx.x;
    int v = (t < SCAN_NB) ? bsums[t] : 0;
    tmp[t] = v;
    __syncthreads();
#pragma unroll
    for (int off = 1; off < 1024; off <<= 1) {
        int s = (t >= off) ? tmp[t - off] : 0;
        __syncthreads();
        tmp[t] += s;
        __syncthreads();
    }
    if (t < SCAN_NB) bsums[t] = tmp[t] - v;          // exclusive
}

__global__ void scan_add(int* __restrict__ starts, const int* __restrict__ bsums) {
    int idx = blockIdx.x * 256 + threadIdx.x;
    if (idx < KN) starts[idx] += bsums[blockIdx.x];
}

__global__ void csr_fill(const int* __restrict__ ei, const float* __restrict__ w,
                         const float* __restrict__ dinv,
                         int* __restrict__ starts, int2* __restrict__ edata) {
    int i = blockIdx.x * blockDim.x + threadIdx.x;
    if (i >= KD * EE) return;
    int k = i / EE, e = i - k * EE;
    const int* eik = ei + (size_t)k * 2 * EE;
    int row = eik[e], col = eik[EE + e];
    float nv = dinv[k * NN + col] * w[i] * dinv[k * NN + row];
    int pos = atomicAdd(&starts[k * NN + col], 1);
    edata[pos] = make_int2(row, __float_as_int(nv));
}

// ---------------- gather aggregation (latency-pipelined) ----------------
__device__ __forceinline__ void fma_row(float4& acc, uint2 w, float nv) {
    __hip_bfloat162 h0 = *(__hip_bfloat162*)&w.x;
    __hip_bfloat162 h1 = *(__hip_bfloat162*)&w.y;
    float2 f0 = __bfloat1622float2(h0), f1 = __bfloat1622float2(h1);
    acc.x += nv * f0.x; acc.y += nv * f0.y;
    acc.z += nv * f1.x; acc.w += nv * f1.y;
}

__global__ __launch_bounds__(256) void gather_agg(
        const int* __restrict__ starts, const int2* __restrict__ edata,
        const u16* __restrict__ xw, u16* __restrict__ xs) {
    int widx = blockIdx.x * 4 + (threadIdx.x >> 6);
    if (widx >= KN) return;
    int lane = threadIdx.x & 63;
    int begin = widx ? starts[widx - 1] : 0;
    int end = starts[widx];
    int deg = end - begin;
    float4 acc = make_float4(0.f, 0.f, 0.f, 0.f);

    // lane-parallel prefetch of up to 64 edge records (breaks addr dependency)
    int2 ed = (lane < deg) ? edata[begin + lane] : make_int2(0, 0);
    int dmain = deg > 64 ? 64 : deg;

    int j = 0;
    for (; j + 4 <= dmain; j += 4) {
        int r0 = __shfl(ed.x, j),     r1 = __shfl(ed.x, j + 1);
        int r2 = __shfl(ed.x, j + 2), r3 = __shfl(ed.x, j + 3);
        float n0 = __int_as_float(__shfl(ed.y, j));
        float n1 = __int_as_float(__shfl(ed.y, j + 1));
        float n2 = __int_as_float(__shfl(ed.y, j + 2));
        float n3 = __int_as_float(__shfl(ed.y, j + 3));
        uint2 w0 = *(const uint2*)(xw + (size_t)r0 * DD + lane * 4);
        uint2 w1 = *(const uint2*)(xw + (size_t)r1 * DD + lane * 4);
        uint2 w2 = *(const uint2*)(xw + (size_t)r2 * DD + lane * 4);
        uint2 w3 = *(const uint2*)(xw + (size_t)r3 * DD + lane * 4);
        fma_row(acc, w0, n0);
        fma_row(acc, w1, n1);
        fma_row(acc, w2, n2);
        fma_row(acc, w3, n3);
    }
    for (; j < dmain; ++j) {
        int r = __shfl(ed.x, j);
        float nv = __int_as_float(__shfl(ed.y, j));
        uint2 w = *(const uint2*)(xw + (size_t)r * DD + lane * 4);
        fma_row(acc, w, nv);
    }
    for (int e = begin + 64; e < end; ++e) {     // rare: deg > 64
        int2 ee = edata[e];
        float nv = __int_as_float(ee.y);
        uint2 w = *(const uint2*)(xw + (size_t)ee.x * DD + lane * 4);
        fma_row(acc, w, nv);
    }

    u64 st = (u64)((u32)f2bf(acc.x) | ((u32)f2bf(acc.y) << 16)) |
             ((u64)((u32)f2bf(acc.z) | ((u32)f2bf(acc.w) << 16)) << 32);
    __builtin_nontemporal_store(st, (u64*)(xs + (size_t)widx * DD + lane * 4));
}

// ---------------- merged weight convert+transpose for ALL weights ----------------
#define GCN_T (LL * DD * DD)                 // 196608
#define ATT_T (LL * KD * DD * ATTD)          // 98304
#define P1_T  (DD * HH1)                     // 32768
#define P2_T  (HH1 * HH2)                    // 8192
#define WC_TOTAL (GCN_T + ATT_T + P1_T + P2_T)
__device__ __forceinline__ void wconv1(const float* __restrict__ W, u16* __restrict__ Wt,
                                       int i, int Kd, int Nc) {
    int kk = i / Nc, n = i - kk * Nc;
    Wt[(size_t)n * Kd + kk] = f2bf(W[i]);
}
__global__ void wconv_all(const float* __restrict__ gcnW, u16* __restrict__ gcnWb,
                          const float* __restrict__ attW, u16* __restrict__ attWb,
                          const float* __restrict__ pW1, u16* __restrict__ pW1b,
                          const float* __restrict__ pW2, u16* __restrict__ pW2b) {
    int gid = blockIdx.x * 256 + threadIdx.x;
    if (gid >= WC_TOTAL) return;
    if (gid < GCN_T) {
        int l = gid >> 16, i = gid & 65535;
        wconv1(gcnW + (size_t)l * DD * DD, gcnWb + (size_t)l * DD * DD, i, DD, DD);
    } else if (gid < GCN_T + ATT_T) {
        int g = gid - GCN_T;
        int lk = g >> 14, i = g & 16383;
        wconv1(attW + (size_t)lk * DD * ATTD, attWb + (size_t)lk * ATTD * DD, i, DD, ATTD);
    } else if (gid < GCN_T + ATT_T + P1_T) {
        wconv1(pW1, pW1b, gid - (GCN_T + ATT_T), DD, HH1);
    } else {
        wconv1(pW2, pW2b, gid - (GCN_T + ATT_T + P1_T), HH1, HH2);
    }
}

// ---------------- fold gcn_b into attention bias ----------------
__global__ void att_bias_fold(const float* __restrict__ attW, const float* __restrict__ attb,
                              const float* __restrict__ gcnb, float* __restrict__ batt) {
    int lk = blockIdx.x;          // 0..5
    int a = threadIdx.x;          // 0..63
    int l = lk >> 1;
    const float* W = attW + (size_t)lk * DD * ATTD;
    const float* gb = gcnb + l * DD;
    float s = attb[lk * ATTD + a];
    for (int d = 0; d < DD; ++d) s += gb[d] * W[d * ATTD + a];
    batt[lk * ATTD + a] = s;
}

#define LDSP 40   // LDS row stride in u16 (32 + 8 pad)

// ---------------- MFMA GEMM, BM=64, 4 waves laid out 1x4 across columns ----------------
// C(M x Nc) = A @ B, B pre-transposed bf16 Bt[n][k].
// PRESPLIT: A pre-split bf16 hi/lo planes (pure-copy staging); else fp32 A runtime split.
// MODE 0: store fp32 C (opt bias/act). MODE 1: store bf16 Cb.
template<int BN_, int MODE, bool PRESPLIT, bool BIAS, int ACT>
__global__ __launch_bounds__(256) void gemm_mfma(
        const float* __restrict__ A,
        const u16* __restrict__ Ahi, const u16* __restrict__ Alo,
        const u16* __restrict__ Bt, const float* __restrict__ bias,
        float* __restrict__ Cf, u16* __restrict__ Cb,
        int M, int Kd, int Nc) {
    constexpr int JW = BN_ / 64;           // j-frags per wave (wave covers BN_/4 cols)
    __shared__ u16 AsHi[64 * LDSP];
    __shared__ u16 AsLo[64 * LDSP];
    __shared__ u16 Bs[BN_ * LDSP];

    const int tid = threadIdx.x;
    const int lane = tid & 63, wx = tid >> 6;      // wave id 0..3 across columns
    const int lane15 = lane & 15, quad = lane >> 4;
    const int bm = blockIdx.x * 64;
    const int bn = blockIdx.y * BN_;

    floatx4 acc[4][JW];
#pragma unroll
    for (int i = 0; i < 4; ++i)
#pragma unroll
        for (int j = 0; j < JW; ++j) acc[i][j] = (floatx4){0.f, 0.f, 0.f, 0.f};

    for (int k0 = 0; k0 < Kd; k0 += 32) {
        if constexpr (PRESPLIT) {
            {   // 64 rows x 32 u16 per plane = 256 uint4 each; 1 per thread
                int m = tid >> 2, ko = (tid & 3) << 3;
                uint4 vh = make_uint4(0, 0, 0, 0), vl = make_uint4(0, 0, 0, 0);
                if (bm + m < M) {
                    vh = *(const uint4*)(Ahi + (size_t)(bm + m) * Kd + k0 + ko);
                    vl = *(const uint4*)(Alo + (size_t)(bm + m) * Kd + k0 + ko);
                }
                *(uint4*)(void*)(AsHi + m * LDSP + ko) = vh;
                *(uint4*)(void*)(AsLo + m * LDSP + ko) = vl;
            }
        } else {
#pragma unroll
            for (int t = tid; t < 512; t += 256) {
                int m = t >> 3, k4 = (t & 7) << 2;
                float4 v = make_float4(0.f, 0.f, 0.f, 0.f);
                if (bm + m < M) v = *(const float4*)(A + (size_t)(bm + m) * Kd + k0 + k4);
                u16 h0 = f2bf(v.x), h1 = f2bf(v.y), h2 = f2bf(v.z), h3 = f2bf(v.w);
                *(ushort4*)(void*)(AsHi + m * LDSP + k4) = make_ushort4(h0, h1, h2, h3);
                u16 l0 = f2bf(v.x - bf2f(h0)), l1 = f2bf(v.y - bf2f(h1));
                u16 l2 = f2bf(v.z - bf2f(h2)), l3 = f2bf(v.w - bf2f(h3));
                *(ushort4*)(void*)(AsLo + m * LDSP + k4) = make_ushort4(l0, l1, l2, l3);
            }
        }
#pragma unroll
        for (int t = tid; t < BN_ * 4; t += 256) {
            int n = t >> 2, ko = (t & 3) << 3;
            uint4 w = *(const uint4*)(Bt + (size_t)(bn + n) * Kd + k0 + ko);
            *(uint4*)(void*)(Bs + n * LDSP + ko) = w;
        }
        __syncthreads();

        const u16* pA  = AsHi + lane15 * LDSP + quad * 8;
        const u16* pAl = AsLo + lane15 * LDSP + quad * 8;
        const u16* pB  = Bs + (wx * (BN_ / 4) + lane15) * LDSP + quad * 8;
        short8 b[JW];
#pragma unroll
        for (int j = 0; j < JW; ++j) b[j] = *(const short8*)(pB + j * 16 * LDSP);
#pragma unroll
        for (int i = 0; i < 4; ++i) {
            short8 a = *(const short8*)(pA + i * 16 * LDSP);
#pragma unroll
            for (int j = 0; j < JW; ++j)
                acc[i][j] = __builtin_amdgcn_mfma_f32_16x16x32_bf16(a, b[j], acc[i][j], 0, 0, 0);
        }
#pragma unroll
        for (int i = 0; i < 4; ++i) {
            short8 a = *(const short8*)(pAl + i * 16 * LDSP);
#pragma unroll
            for (int j = 0; j < JW; ++j)
                acc[i][j] = __builtin_amdgcn_mfma_f32_16x16x32_bf16(a, b[j], acc[i][j], 0, 0, 0);
        }
        __syncthreads();
    }

#pragma unroll
    for (int i = 0; i < 4; ++i) {
#pragma unroll
        for (int r = 0; r < 4; ++r) {
            int row = bm + i * 16 + quad * 4 + r;
            if (row >= M) continue;
#pragma unroll
            for (int j = 0; j < JW; ++j) {
                int col = bn + wx * (BN_ / 4) + j * 16 + lane15;
                float v = acc[i][j][r];
                if constexpr (BIAS) v += bias[col];
                if constexpr (ACT == 1) v = v > 0.f ? v : SLOPE * v;
                if constexpr (MODE == 0) Cf[(size_t)row * Nc + col] = v;
                else                     Cb[(size_t)row * Nc + col] = f2bf(v);
            }
        }
    }
}

// ---------------- fused attention: keys/tanh/sim both k, softmax, combine, relu ----------------
__global__ __launch_bounds__(256) void att_combine(
        const u16* __restrict__ xs, const u16* __restrict__ Bt,
        const float* __restrict__ batt, const float* __restrict__ qv,
        const float* __restrict__ gcnb,
        u16* __restrict__ h_hi, u16* __restrict__ h_lo) {
    __shared__ u16 As[KD][128 * LDSP];
    __shared__ u16 Bs[KD][ATTD * LDSP];
    __shared__ float simbuf[KD][4][64];

    const int tid = threadIdx.x;
    const int lane = tid & 63, waveid = tid >> 6;
    const int wy = waveid >> 1, wx = waveid & 1;
    const int lane15 = lane & 15, quad = lane >> 4;
    const int bm = blockIdx.x * 128;

    floatx4 acc[KD][4][2];
#pragma unroll
    for (int k = 0; k < KD; ++k)
#pragma unroll
        for (int i = 0; i < 4; ++i)
#pragma unroll
            for (int j = 0; j < 2; ++j) acc[k][i][j] = (floatx4){0.f, 0.f, 0.f, 0.f};

    for (int k0 = 0; k0 < DD; k0 += 32) {
#pragma unroll
        for (int k = 0; k < KD; ++k) {
#pragma unroll
            for (int t = tid; t < 512; t += 256) {
                int m = t >> 2, ko = (t & 3) << 3;
                uint4 v = make_uint4(0, 0, 0, 0);
                if (bm + m < NN)
                    v = *(const uint4*)(xs + ((size_t)k * NN + bm + m) * DD + k0 + ko);
                *(uint4*)(void*)(As[k] + m * LDSP + ko) = v;
            }
            {
                int n = tid >> 2, ko = (tid & 3) << 3;
                uint4 w = *(const uint4*)(Bt + (size_t)k * ATTD * DD + (size_t)n * DD + k0 + ko);
                *(uint4*)(void*)(Bs[k] + n * LDSP + ko) = w;
            }
        }
        __syncthreads();
#pragma unroll
        for (int k = 0; k < KD; ++k) {
            const u16* pA = As[k] + (wy * 64 + lane15) * LDSP + quad * 8;
            const u16* pB = Bs[k] + (wx * 32 + lane15) * LDSP + quad * 8;
            short8 b[2];
            b[0] = *(const short8*)(pB);
            b[1] = *(const short8*)(pB + 16 * LDSP);
#pragma unroll
            for (int i = 0; i < 4; ++i) {
                short8 a = *(const short8*)(pA + i * 16 * LDSP);
                acc[k][i][0] = __builtin_amdgcn_mfma_f32_16x16x32_bf16(a, b[0], acc[k][i][0], 0, 0, 0);
                acc[k][i][1] = __builtin_amdgcn_mfma_f32_16x16x32_bf16(a, b[1], acc[k][i][1], 0, 0, 0);
            }
        }
        __syncthreads();
    }

#pragma unroll
    for (int k = 0; k < KD; ++k) {
#pragma unroll
        for (int i = 0; i < 4; ++i) {
#pragma unroll
            for (int r = 0; r < 4; ++r) {
                float p = 0.f;
#pragma unroll
                for (int j = 0; j < 2; ++j) {
                    int col = wx * 32 + j * 16 + lane15;
                    float v = acc[k][i][j][r] + batt[k * ATTD + col];
                    p += tanhf(v) * qv[k * ATTD + col];
                }
                p += __shfl_xor(p, 1, 64);
                p += __shfl_xor(p, 2, 64);
                p += __shfl_xor(p, 4, 64);
                p += __shfl_xor(p, 8, 64);
                if (lane15 == 0) simbuf[k][wy * 2 + wx][i * 16 + quad * 4 + r] = p;
            }
        }
    }
    __syncthreads();

#pragma unroll 4
    for (int it = 0; it < 32; ++it) {
        int item = tid + it * 256;
        int row = item >> 6, dq = item & 63;
        int grow = bm + row;
        if (grow >= NN) continue;
        int wy2 = row >> 6, rl = row & 63;
        float s0 = simbuf[0][wy2 * 2 + 0][rl] + simbuf[0][wy2 * 2 + 1][rl];
        float s1 = simbuf[1][wy2 * 2 + 0][rl] + simbuf[1][wy2 * 2 + 1][rl];
        float m = fmaxf(s0, s1);
        float e0 = __expf(s0 - m), e1 = __expf(s1 - m);
        float inv = 1.f / (e0 + e1);
        float a0 = e0 * inv, a1 = e1 * inv;
        const __hip_bfloat162* p0 = (const __hip_bfloat162*)(xs + (size_t)grow * DD + dq * 4);
        const __hip_bfloat162* p1 = (const __hip_bfloat162*)(xs + ((size_t)NN + grow) * DD + dq * 4);
        float2 v00 = __bfloat1622float2(p0[0]), v01 = __bfloat1622float2(p0[1]);
        float2 v10 = __bfloat1622float2(p1[0]), v11 = __bfloat1622float2(p1[1]);
        float4 bv = ((const float4*)gcnb)[dq];
        float r0 = fmaxf(0.f, a0 * v00.x + a1 * v10.x + bv.x);
        float r1 = fmaxf(0.f, a0 * v00.y + a1 * v10.y + bv.y);
        float r2 = fmaxf(0.f, a0 * v01.x + a1 * v11.x + bv.z);
        float r3 = fmaxf(0.f, a0 * v01.y + a1 * v11.y + bv.w);
        u16 hb0 = f2bf(r0), hb1 = f2bf(r1), hb2 = f2bf(r2), hb3 = f2bf(r3);
        *(ushort4*)(h_hi + (size_t)grow * DD + dq * 4) = make_ushort4(hb0, hb1, hb2, hb3);
        *(ushort4*)(h_lo + (size_t)grow * DD + dq * 4) =
            make_ushort4(f2bf(r0 - bf2f(hb0)), f2bf(r1 - bf2f(hb1)),
                         f2bf(r2 - bf2f(hb2)), f2bf(r3 - bf2f(hb3)));
    }
}

extern "C" void kernel_launch(void* const* d_in, const int* in_sizes, int n_in,
                              void* d_out, int out_size, void* d_ws, size_t ws_size,
                              hipStream_t stream) {
    const float* x     = (const float*)d_in[0];
    const int*   ei    = (const int*)d_in[1];
    const float* ew    = (const float*)d_in[2];
    const float* gamma = (const float*)d_in[3];
    const float* beta  = (const float*)d_in[4];
    const float* gcn_W = (const float*)d_in[5];
    const float* gcn_b = (const float*)d_in[6];
    const float* att_W = (const float*)d_in[7];
    const float* att_b = (const float*)d_in[8];
    const float* att_q = (const float*)d_in[9];
    const float* pW1   = (const float*)d_in[10];
    const float* pb1   = (const float*)d_in[11];
    const float* pW2   = (const float*)d_in[12];
    const float* pb2   = (const float*)d_in[13];
    float* out = (float*)d_out;

    char* wsb = (char*)d_ws;
    size_t off = 0;
    auto alloc = [&](size_t bytes) -> void* {
        void* p = wsb + off;
        off += (bytes + 255) & ~(size_t)255;
        return p;
    };
    u16*   xs    = (u16*)alloc((size_t)KD * NN * DD * 2);     // 102.4 MB (bf16)
    u16*   h_hi  = (u16*)alloc((size_t)NN * DD * 2);          // 51.2 MB
    u16*   h_lo  = (u16*)alloc((size_t)NN * DD * 2);          // 51.2 MB
    u16*   xw    = (u16*)alloc((size_t)NN * DD * 2);          // 51.2 MB
    float* p1tmp = (float*)xw;                                // N*H1*4, exact reuse
    float* dinv  = (float*)alloc((size_t)KN * 4);             // adjacent to starts
    int*   starts= (int*)alloc(((size_t)KN + 1) * 4);
    int2*  edata = (int2*)alloc((size_t)KD * EE * 8);         // 6.4 MB
    float* bnsums= (float*)alloc(2 * DD * 4);
    u16*   gcnWb = (u16*)alloc((size_t)LL * DD * DD * 2);
    u16*   attWb = (u16*)alloc((size_t)LL * KD * ATTD * DD * 2);
    u16*   pW1b  = (u16*)alloc((size_t)HH1 * DD * 2);
    u16*   pW2b  = (u16*)alloc((size_t)HH2 * HH1 * 2);
    float* batt  = (float*)alloc((size_t)LL * KD * ATTD * 4);
    int*   bsums = (int*)alloc((size_t)SCAN_NB * 4);

    // ---- setup: all weight converts in ONE kernel + att bias fold ----
    wconv_all<<<(WC_TOTAL + 255) / 256, 256, 0, stream>>>(
        gcn_W, gcnWb, att_W, attWb, pW1, pW1b, pW2, pW2b);
    att_bias_fold<<<LL * KD, ATTD, 0, stream>>>(att_W, att_b, gcn_b, batt);

    // ---- BatchNorm -> h (pre-split) ----
    hipMemsetAsync(bnsums, 0, 2 * DD * 4, stream);
    bn_stats<<<800, 256, 0, stream>>>(x, bnsums);
    bn_apply<<<25000, 256, 0, stream>>>(x, bnsums, gamma, beta, h_hi, h_lo);

    // ---- degree / CSR (layer-invariant); dinv+starts zeroed in one memset ----
    hipMemsetAsync(dinv, 0, (size_t)KN * 4 + ((size_t)KN + 1) * 4, stream);
    deg_count<<<(KD * EE + 255) / 256, 256, 0, stream>>>(ei, ew, dinv, starts);
    dinv_kernel<<<(KN + 255) / 256, 256, 0, stream>>>(dinv);
    scan_blocks<<<SCAN_NB, 256, 0, stream>>>(starts, bsums);
    scan_sums<<<1, 1024, 0, stream>>>(bsums);
    scan_add<<<SCAN_NB, 256, 0, stream>>>(starts, bsums);
    csr_fill<<<(KD * EE + 255) / 256, 256, 0, stream>>>(ei, ew, dinv, starts, edata);

    const int MB64 = (NN + 63) / 64;     // 1563
    const int MB128 = (NN + 127) / 128;  // 782
    for (int l = 0; l < LL; ++l) {
        // xw(bf16) = h @ gcn_W[l] — BM=64 x BN=256, copy-only staging
        gemm_mfma<256, 1, true, false, 0><<<dim3(MB64, 1), 256, 0, stream>>>(
            nullptr, h_hi, h_lo, gcnWb + (size_t)l * DD * DD, nullptr,
            nullptr, xw, NN, DD, DD);
        gather_agg<<<(KN + 3) / 4, 256, 0, stream>>>(starts, edata, xw, xs);
        att_combine<<<MB128, 256, 0, stream>>>(
            xs, attWb + (size_t)l * KD * ATTD * DD,
            batt + (size_t)l * KD * ATTD, att_q + (size_t)l * KD * ATTD,
            gcn_b + l * DD, h_hi, h_lo);
    }

    // ---- projection head ----
    gemm_mfma<128, 0, true, true, 1><<<dim3(MB64, 1), 256, 0, stream>>>(
        nullptr, h_hi, h_lo, pW1b, pb1, p1tmp, nullptr, NN, DD, HH1);
    gemm_mfma<64, 0, false, true, 1><<<dim3(MB64, 1), 256, 0, stream>>>(
        p1tmp, nullptr, nullptr, pW2b, pb2, out, nullptr, NN, HH1, HH2);
}

// Round 11
// 1064.748 us; speedup vs baseline: 1.2251x; 1.0381x over previous
//
#include <hip/hip_runtime.h>
#include <hip/hip_bf16.h>
#include <math.h>

#define NN 100000
#define EE 400000
#define KD 2
#define DD 256
#define ATTD 64
#define LL 3
#define HH1 128
#define HH2 64
#define EPSV 1e-5f
#define SLOPE 0.01f
#define KN (KD * NN)

typedef short short8 __attribute__((ext_vector_type(8)));
typedef float floatx4 __attribute__((ext_vector_type(4)));
typedef unsigned short u16;
typedef unsigned int u32;
typedef unsigned long long u64;

__device__ __forceinline__ u16 f2bf(float f) {
    u32 u = __float_as_uint(f);
    return (u16)((u + 0x7fffu + ((u >> 16) & 1u)) >> 16);
}
__device__ __forceinline__ float bf2f(u16 h) {
    return __uint_as_float((u32)h << 16);
}

// ---------------- BatchNorm ----------------
__global__ void bn_stats(const float* __restrict__ x, float* __restrict__ sums) {
    int d = threadIdx.x;
    int r0 = blockIdx.x * 125;
    float s = 0.f, sq = 0.f;
    for (int r = r0; r < r0 + 125; ++r) {
        float v = x[(size_t)r * DD + d];
        s += v; sq += v * v;
    }
    atomicAdd(&sums[d], s);
    atomicAdd(&sums[DD + d], sq);
}

// writes h as pre-split bf16 hi/lo planes
__global__ void bn_apply(const float* __restrict__ x, const float* __restrict__ sums,
                         const float* __restrict__ gamma, const float* __restrict__ beta,
                         u16* __restrict__ h_hi, u16* __restrict__ h_lo) {
    size_t i = (size_t)blockIdx.x * blockDim.x + threadIdx.x;
    const float inv_n = 1.f / NN;
    int dq = (int)(i & 63) * 4;
    float4 xv = ((const float4*)x)[i];
    ushort4 hv, lv;
    float* xp = (float*)&xv;
    u16* hp = (u16*)&hv; u16* lp = (u16*)&lv;
#pragma unroll
    for (int j = 0; j < 4; ++j) {
        int d = dq + j;
        float mu = sums[d] * inv_n;
        float var = sums[DD + d] * inv_n - mu * mu;
        float inv = rsqrtf(var + EPSV);
        float v = (xp[j] - mu) * inv * gamma[d] + beta[d];
        u16 hb = f2bf(v);
        hp[j] = hb;
        lp[j] = f2bf(v - bf2f(hb));
    }
    ((ushort4*)h_hi)[i] = hv;
    ((ushort4*)h_lo)[i] = lv;
}

// ---------------- degree + CSR count (merged) ----------------
__global__ void deg_count(const int* __restrict__ ei, const float* __restrict__ w,
                          float* __restrict__ deg, int* __restrict__ counts) {
    int i = blockIdx.x * blockDim.x + threadIdx.x;
    if (i >= KD * EE) return;
    int k = i / EE, e = i - k * EE;
    int col = ei[(size_t)k * 2 * EE + EE + e];
    atomicAdd(&deg[k * NN + col], w[i]);
    atomicAdd(&counts[k * NN + col], 1);
}

__global__ void dinv_kernel(float* __restrict__ d) {
    int i = blockIdx.x * blockDim.x + threadIdx.x;
    if (i >= KD * NN) return;
    float v = d[i];
    d[i] = v > 0.f ? 1.f / sqrtf(v) : 0.f;
}

#define SCAN_NB ((KN + 255) / 256)   // 782
__global__ void scan_blocks(int* __restrict__ starts, int* __restrict__ bsums) {
    __shared__ int tmp[256];
    int t = threadIdx.x;
    int idx = blockIdx.x * 256 + t;
    int v = (idx < KN) ? starts[idx] : 0;
    tmp[t] = v;
    __syncthreads();
#pragma unroll
    for (int off = 1; off < 256; off <<= 1) {
        int s = (t >= off) ? tmp[t - off] : 0;
        __syncthreads();
        tmp[t] += s;
        __syncthreads();
    }
    if (idx < KN) starts[idx] = tmp[t] - v;          // exclusive
    if (t == 255) bsums[blockIdx.x] = tmp[255];      // block total
}

__global__ void scan_sums(int* __restrict__ bsums) {
    __shared__ int tmp[1024];
    int t = threadIdx.x;
    int v = (t < SCAN_NB) ? bsums[t] : 0;
    tmp[t] = v;
    __syncthreads();
#pragma unroll
    for (int off = 1; off < 1024; off <<= 1) {
        int s = (t >= off) ? tmp[t - off] : 0;
        __syncthreads();
        tmp[t] += s;
        __syncthreads();
    }
    if (t < SCAN_NB) bsums[t] = tmp[t] - v;          // exclusive
}

__global__ void scan_add(int* __restrict__ starts, const int* __restrict__ bsums) {
    int idx = blockIdx.x * 256 + threadIdx.x;
    if (idx < KN) starts[idx] += bsums[blockIdx.x];
}

__global__ void csr_fill(const int* __restrict__ ei, const float* __restrict__ w,
                         const float* __restrict__ dinv,
                         int* __restrict__ starts, int2* __restrict__ edata) {
    int i = blockIdx.x * blockDim.x + threadIdx.x;
    if (i >= KD * EE) return;
    int k = i / EE, e = i - k * EE;
    const int* eik = ei + (size_t)k * 2 * EE;
    int row = eik[e], col = eik[EE + e];
    float nv = dinv[k * NN + col] * w[i] * dinv[k * NN + row];
    int pos = atomicAdd(&starts[k * NN + col], 1);
    edata[pos] = make_int2(row, __float_as_int(nv));
}

// ---------------- gather aggregation (latency-pipelined) ----------------
__device__ __forceinline__ void fma_row(float4& acc, uint2 w, float nv) {
    __hip_bfloat162 h0 = *(__hip_bfloat162*)&w.x;
    __hip_bfloat162 h1 = *(__hip_bfloat162*)&w.y;
    float2 f0 = __bfloat1622float2(h0), f1 = __bfloat1622float2(h1);
    acc.x += nv * f0.x; acc.y += nv * f0.y;
    acc.z += nv * f1.x; acc.w += nv * f1.y;
}

__global__ __launch_bounds__(256) void gather_agg(
        const int* __restrict__ starts, const int2* __restrict__ edata,
        const u16* __restrict__ xw, u16* __restrict__ xs) {
    int widx = blockIdx.x * 4 + (threadIdx.x >> 6);
    if (widx >= KN) return;
    int lane = threadIdx.x & 63;
    int begin = widx ? starts[widx - 1] : 0;
    int end = starts[widx];
    int deg = end - begin;
    float4 acc = make_float4(0.f, 0.f, 0.f, 0.f);

    // lane-parallel prefetch of up to 64 edge records (breaks addr dependency)
    int2 ed = (lane < deg) ? edata[begin + lane] : make_int2(0, 0);
    int dmain = deg > 64 ? 64 : deg;

    int j = 0;
    for (; j + 4 <= dmain; j += 4) {
        int r0 = __shfl(ed.x, j),     r1 = __shfl(ed.x, j + 1);
        int r2 = __shfl(ed.x, j + 2), r3 = __shfl(ed.x, j + 3);
        float n0 = __int_as_float(__shfl(ed.y, j));
        float n1 = __int_as_float(__shfl(ed.y, j + 1));
        float n2 = __int_as_float(__shfl(ed.y, j + 2));
        float n3 = __int_as_float(__shfl(ed.y, j + 3));
        uint2 w0 = *(const uint2*)(xw + (size_t)r0 * DD + lane * 4);
        uint2 w1 = *(const uint2*)(xw + (size_t)r1 * DD + lane * 4);
        uint2 w2 = *(const uint2*)(xw + (size_t)r2 * DD + lane * 4);
        uint2 w3 = *(const uint2*)(xw + (size_t)r3 * DD + lane * 4);
        fma_row(acc, w0, n0);
        fma_row(acc, w1, n1);
        fma_row(acc, w2, n2);
        fma_row(acc, w3, n3);
    }
    for (; j < dmain; ++j) {
        int r = __shfl(ed.x, j);
        float nv = __int_as_float(__shfl(ed.y, j));
        uint2 w = *(const uint2*)(xw + (size_t)r * DD + lane * 4);
        fma_row(acc, w, nv);
    }
    for (int e = begin + 64; e < end; ++e) {     // rare: deg > 64
        int2 ee = edata[e];
        float nv = __int_as_float(ee.y);
        uint2 w = *(const uint2*)(xw + (size_t)ee.x * DD + lane * 4);
        fma_row(acc, w, nv);
    }

    u64 st = (u64)((u32)f2bf(acc.x) | ((u32)f2bf(acc.y) << 16)) |
             ((u64)((u32)f2bf(acc.z) | ((u32)f2bf(acc.w) << 16)) << 32);
    __builtin_nontemporal_store(st, (u64*)(xs + (size_t)widx * DD + lane * 4));
}

// ---------------- merged weight convert+transpose for ALL weights ----------------
#define GCN_T (LL * DD * DD)                 // 196608
#define ATT_T (LL * KD * DD * ATTD)          // 98304
#define P1_T  (DD * HH1)                     // 32768
#define P2_T  (HH1 * HH2)                    // 8192
#define WC_TOTAL (GCN_T + ATT_T + P1_T + P2_T)
__device__ __forceinline__ void wconv1(const float* __restrict__ W, u16* __restrict__ Wt,
                                       int i, int Kd, int Nc) {
    int kk = i / Nc, n = i - kk * Nc;
    Wt[(size_t)n * Kd + kk] = f2bf(W[i]);
}
__global__ void wconv_all(const float* __restrict__ gcnW, u16* __restrict__ gcnWb,
                          const float* __restrict__ attW, u16* __restrict__ attWb,
                          const float* __restrict__ pW1, u16* __restrict__ pW1b,
                          const float* __restrict__ pW2, u16* __restrict__ pW2b) {
    int gid = blockIdx.x * 256 + threadIdx.x;
    if (gid >= WC_TOTAL) return;
    if (gid < GCN_T) {
        int l = gid >> 16, i = gid & 65535;
        wconv1(gcnW + (size_t)l * DD * DD, gcnWb + (size_t)l * DD * DD, i, DD, DD);
    } else if (gid < GCN_T + ATT_T) {
        int g = gid - GCN_T;
        int lk = g >> 14, i = g & 16383;
        wconv1(attW + (size_t)lk * DD * ATTD, attWb + (size_t)lk * ATTD * DD, i, DD, ATTD);
    } else if (gid < GCN_T + ATT_T + P1_T) {
        wconv1(pW1, pW1b, gid - (GCN_T + ATT_T), DD, HH1);
    } else {
        wconv1(pW2, pW2b, gid - (GCN_T + ATT_T + P1_T), HH1, HH2);
    }
}

// ---------------- fold gcn_b into attention bias ----------------
__global__ void att_bias_fold(const float* __restrict__ attW, const float* __restrict__ attb,
                              const float* __restrict__ gcnb, float* __restrict__ batt) {
    int lk = blockIdx.x;          // 0..5
    int a = threadIdx.x;          // 0..63
    int l = lk >> 1;
    const float* W = attW + (size_t)lk * DD * ATTD;
    const float* gb = gcnb + l * DD;
    float s = attb[lk * ATTD + a];
    for (int d = 0; d < DD; ++d) s += gb[d] * W[d * ATTD + a];
    batt[lk * ATTD + a] = s;
}

#define LDSP 40   // LDS row stride in u16 (32 + 8 pad)

// ---------------- MFMA GEMM, BM=64, 4 waves laid out 1x4 across columns ----------------
template<int BN_, int MODE, bool PRESPLIT, bool BIAS, int ACT>
__global__ __launch_bounds__(256) void gemm_mfma(
        const float* __restrict__ A,
        const u16* __restrict__ Ahi, const u16* __restrict__ Alo,
        const u16* __restrict__ Bt, const float* __restrict__ bias,
        float* __restrict__ Cf, u16* __restrict__ Cb,
        int M, int Kd, int Nc) {
    constexpr int JW = BN_ / 64;           // j-frags per wave (wave covers BN_/4 cols)
    __shared__ u16 AsHi[64 * LDSP];
    __shared__ u16 AsLo[64 * LDSP];
    __shared__ u16 Bs[BN_ * LDSP];

    const int tid = threadIdx.x;
    const int lane = tid & 63, wx = tid >> 6;      // wave id 0..3 across columns
    const int lane15 = lane & 15, quad = lane >> 4;
    const int bm = blockIdx.x * 64;
    const int bn = blockIdx.y * BN_;

    floatx4 acc[4][JW];
#pragma unroll
    for (int i = 0; i < 4; ++i)
#pragma unroll
        for (int j = 0; j < JW; ++j) acc[i][j] = (floatx4){0.f, 0.f, 0.f, 0.f};

    for (int k0 = 0; k0 < Kd; k0 += 32) {
        if constexpr (PRESPLIT) {
            {   // 64 rows x 32 u16 per plane = 256 uint4 each; 1 per thread
                int m = tid >> 2, ko = (tid & 3) << 3;
                uint4 vh = make_uint4(0, 0, 0, 0), vl = make_uint4(0, 0, 0, 0);
                if (bm + m < M) {
                    vh = *(const uint4*)(Ahi + (size_t)(bm + m) * Kd + k0 + ko);
                    vl = *(const uint4*)(Alo + (size_t)(bm + m) * Kd + k0 + ko);
                }
                *(uint4*)(void*)(AsHi + m * LDSP + ko) = vh;
                *(uint4*)(void*)(AsLo + m * LDSP + ko) = vl;
            }
        } else {
#pragma unroll
            for (int t = tid; t < 512; t += 256) {
                int m = t >> 3, k4 = (t & 7) << 2;
                float4 v = make_float4(0.f, 0.f, 0.f, 0.f);
                if (bm + m < M) v = *(const float4*)(A + (size_t)(bm + m) * Kd + k0 + k4);
                u16 h0 = f2bf(v.x), h1 = f2bf(v.y), h2 = f2bf(v.z), h3 = f2bf(v.w);
                *(ushort4*)(void*)(AsHi + m * LDSP + k4) = make_ushort4(h0, h1, h2, h3);
                u16 l0 = f2bf(v.x - bf2f(h0)), l1 = f2bf(v.y - bf2f(h1));
                u16 l2 = f2bf(v.z - bf2f(h2)), l3 = f2bf(v.w - bf2f(h3));
                *(ushort4*)(void*)(AsLo + m * LDSP + k4) = make_ushort4(l0, l1, l2, l3);
            }
        }
#pragma unroll
        for (int t = tid; t < BN_ * 4; t += 256) {
            int n = t >> 2, ko = (t & 3) << 3;
            uint4 w = *(const uint4*)(Bt + (size_t)(bn + n) * Kd + k0 + ko);
            *(uint4*)(void*)(Bs + n * LDSP + ko) = w;
        }
        __syncthreads();

        const u16* pA  = AsHi + lane15 * LDSP + quad * 8;
        const u16* pAl = AsLo + lane15 * LDSP + quad * 8;
        const u16* pB  = Bs + (wx * (BN_ / 4) + lane15) * LDSP + quad * 8;
        short8 b[JW];
#pragma unroll
        for (int j = 0; j < JW; ++j) b[j] = *(const short8*)(pB + j * 16 * LDSP);
#pragma unroll
        for (int i = 0; i < 4; ++i) {
            short8 a = *(const short8*)(pA + i * 16 * LDSP);
#pragma unroll
            for (int j = 0; j < JW; ++j)
                acc[i][j] = __builtin_amdgcn_mfma_f32_16x16x32_bf16(a, b[j], acc[i][j], 0, 0, 0);
        }
#pragma unroll
        for (int i = 0; i < 4; ++i) {
            short8 a = *(const short8*)(pAl + i * 16 * LDSP);
#pragma unroll
            for (int j = 0; j < JW; ++j)
                acc[i][j] = __builtin_amdgcn_mfma_f32_16x16x32_bf16(a, b[j], acc[i][j], 0, 0, 0);
        }
        __syncthreads();
    }

#pragma unroll
    for (int i = 0; i < 4; ++i) {
#pragma unroll
        for (int r = 0; r < 4; ++r) {
            int row = bm + i * 16 + quad * 4 + r;
            if (row >= M) continue;
#pragma unroll
            for (int j = 0; j < JW; ++j) {
                int col = bn + wx * (BN_ / 4) + j * 16 + lane15;
                float v = acc[i][j][r];
                if constexpr (BIAS) v += bias[col];
                if constexpr (ACT == 1) v = v > 0.f ? v : SLOPE * v;
                if constexpr (MODE == 0) Cf[(size_t)row * Nc + col] = v;
                else                     Cb[(size_t)row * Nc + col] = f2bf(v);
            }
        }
    }
}

// ---------------- fused attention v2: 64-row tile, full-row LDS, B in regs ----------------
// waveid: kw = waveid>>1 (which k), ch = waveid&1 (column half)
// 2 barriers total. Combine phase reads xs from LDS. Fast tanh.
#define ALDS 264   // full-row stride in u16 (256 + 8 pad -> 4-dword bank step)
__global__ __launch_bounds__(256) void att_combine(
        const u16* __restrict__ xs, const u16* __restrict__ Bt,
        const float* __restrict__ batt, const float* __restrict__ qv,
        const float* __restrict__ gcnb,
        u16* __restrict__ h_hi, u16* __restrict__ h_lo) {
    __shared__ u16 As[KD * 64 * ALDS];           // 67.6 KB
    __shared__ float simbuf[KD][2][64];

    const int tid = threadIdx.x;
    const int lane = tid & 63, waveid = tid >> 6;
    const int kw = waveid >> 1, ch = waveid & 1;
    const int lane15 = lane & 15, quad = lane >> 4;
    const int bm = blockIdx.x * 64;

    // preload all B fragments into registers (global reads, L2-hot weights)
    short8 bf[8][2];
#pragma unroll
    for (int t = 0; t < 8; ++t)
#pragma unroll
        for (int j = 0; j < 2; ++j) {
            int col = ch * 32 + j * 16 + lane15;
            bf[t][j] = *(const short8*)(Bt + (size_t)kw * ATTD * DD +
                                        (size_t)col * DD + t * 32 + quad * 8);
        }

    // stage full xs rows for both k, coalesced (4096 uint4 / 256 threads = 16 each)
#pragma unroll
    for (int it = 0; it < 16; ++it) {
        int item = tid + it * 256;
        int k = item >> 11, r = (item >> 5) & 63, c = item & 31;
        uint4 v = make_uint4(0, 0, 0, 0);
        if (bm + r < NN)
            v = *(const uint4*)(xs + ((size_t)k * NN + bm + r) * DD + c * 8);
        *(uint4*)(void*)(As + (k * 64 + r) * ALDS + c * 8) = v;
    }
    __syncthreads();

    floatx4 acc[4][2];
#pragma unroll
    for (int i = 0; i < 4; ++i)
#pragma unroll
        for (int j = 0; j < 2; ++j) acc[i][j] = (floatx4){0.f, 0.f, 0.f, 0.f};

#pragma unroll
    for (int t = 0; t < 8; ++t) {
#pragma unroll
        for (int i = 0; i < 4; ++i) {
            short8 a = *(const short8*)(As + (kw * 64 + i * 16 + lane15) * ALDS +
                                        t * 32 + quad * 8);
            acc[i][0] = __builtin_amdgcn_mfma_f32_16x16x32_bf16(a, bf[t][0], acc[i][0], 0, 0, 0);
            acc[i][1] = __builtin_amdgcn_mfma_f32_16x16x32_bf16(a, bf[t][1], acc[i][1], 0, 0, 0);
        }
    }

    // sim: per row sum over this wave's 32 cols of tanh(v+batt)*q
#pragma unroll
    for (int i = 0; i < 4; ++i) {
#pragma unroll
        for (int r = 0; r < 4; ++r) {
            float p = 0.f;
#pragma unroll
            for (int j = 0; j < 2; ++j) {
                int col = ch * 32 + j * 16 + lane15;
                float v = acc[i][j][r] + batt[kw * ATTD + col];
                float ex = __expf(2.f * v);
                float th = 1.f - 2.f / (ex + 1.f);     // tanh, inf-safe
                p += th * qv[kw * ATTD + col];
            }
            p += __shfl_xor(p, 1, 64);
            p += __shfl_xor(p, 2, 64);
            p += __shfl_xor(p, 4, 64);
            p += __shfl_xor(p, 8, 64);
            if (lane15 == 0) simbuf[kw][ch][i * 16 + quad * 4 + r] = p;
        }
    }
    __syncthreads();

    // combine: 64 rows x 64 chunks / 256 threads = 16 items; xs values from LDS
#pragma unroll 4
    for (int it = 0; it < 16; ++it) {
        int item = tid + it * 256;
        int row = item >> 6, dq = item & 63;
        int grow = bm + row;
        if (grow >= NN) continue;
        float s0 = simbuf[0][0][row] + simbuf[0][1][row];
        float s1 = simbuf[1][0][row] + simbuf[1][1][row];
        float m = fmaxf(s0, s1);
        float e0 = __expf(s0 - m), e1 = __expf(s1 - m);
        float inv = 1.f / (e0 + e1);
        float a0 = e0 * inv, a1 = e1 * inv;
        const u16* p0 = As + row * ALDS + dq * 4;
        const u16* p1 = As + (64 + row) * ALDS + dq * 4;
        float4 bv = ((const float4*)gcnb)[dq];
        float r0 = fmaxf(0.f, a0 * bf2f(p0[0]) + a1 * bf2f(p1[0]) + bv.x);
        float r1 = fmaxf(0.f, a0 * bf2f(p0[1]) + a1 * bf2f(p1[1]) + bv.y);
        float r2 = fmaxf(0.f, a0 * bf2f(p0[2]) + a1 * bf2f(p1[2]) + bv.z);
        float r3 = fmaxf(0.f, a0 * bf2f(p0[3]) + a1 * bf2f(p1[3]) + bv.w);
        u16 hb0 = f2bf(r0), hb1 = f2bf(r1), hb2 = f2bf(r2), hb3 = f2bf(r3);
        *(ushort4*)(h_hi + (size_t)grow * DD + dq * 4) = make_ushort4(hb0, hb1, hb2, hb3);
        *(ushort4*)(h_lo + (size_t)grow * DD + dq * 4) =
            make_ushort4(f2bf(r0 - bf2f(hb0)), f2bf(r1 - bf2f(hb1)),
                         f2bf(r2 - bf2f(hb2)), f2bf(r3 - bf2f(hb3)));
    }
}

extern "C" void kernel_launch(void* const* d_in, const int* in_sizes, int n_in,
                              void* d_out, int out_size, void* d_ws, size_t ws_size,
                              hipStream_t stream) {
    const float* x     = (const float*)d_in[0];
    const int*   ei    = (const int*)d_in[1];
    const float* ew    = (const float*)d_in[2];
    const float* gamma = (const float*)d_in[3];
    const float* beta  = (const float*)d_in[4];
    const float* gcn_W = (const float*)d_in[5];
    const float* gcn_b = (const float*)d_in[6];
    const float* att_W = (const float*)d_in[7];
    const float* att_b = (const float*)d_in[8];
    const float* att_q = (const float*)d_in[9];
    const float* pW1   = (const float*)d_in[10];
    const float* pb1   = (const float*)d_in[11];
    const float* pW2   = (const float*)d_in[12];
    const float* pb2   = (const float*)d_in[13];
    float* out = (float*)d_out;

    char* wsb = (char*)d_ws;
    size_t off = 0;
    auto alloc = [&](size_t bytes) -> void* {
        void* p = wsb + off;
        off += (bytes + 255) & ~(size_t)255;
        return p;
    };
    u16*   xs    = (u16*)alloc((size_t)KD * NN * DD * 2);     // 102.4 MB (bf16)
    u16*   h_hi  = (u16*)alloc((size_t)NN * DD * 2);          // 51.2 MB
    u16*   h_lo  = (u16*)alloc((size_t)NN * DD * 2);          // 51.2 MB
    u16*   xw    = (u16*)alloc((size_t)NN * DD * 2);          // 51.2 MB
    float* p1tmp = (float*)xw;                                // N*H1*4, exact reuse
    float* dinv  = (float*)alloc((size_t)KN * 4);             // adjacent to starts
    int*   starts= (int*)alloc(((size_t)KN + 1) * 4);
    int2*  edata = (int2*)alloc((size_t)KD * EE * 8);         // 6.4 MB
    float* bnsums= (float*)alloc(2 * DD * 4);
    u16*   gcnWb = (u16*)alloc((size_t)LL * DD * DD * 2);
    u16*   attWb = (u16*)alloc((size_t)LL * KD * ATTD * DD * 2);
    u16*   pW1b  = (u16*)alloc((size_t)HH1 * DD * 2);
    u16*   pW2b  = (u16*)alloc((size_t)HH2 * HH1 * 2);
    float* batt  = (float*)alloc((size_t)LL * KD * ATTD * 4);
    int*   bsums = (int*)alloc((size_t)SCAN_NB * 4);

    // ---- setup: all weight converts in ONE kernel + att bias fold ----
    wconv_all<<<(WC_TOTAL + 255) / 256, 256, 0, stream>>>(
        gcn_W, gcnWb, att_W, attWb, pW1, pW1b, pW2, pW2b);
    att_bias_fold<<<LL * KD, ATTD, 0, stream>>>(att_W, att_b, gcn_b, batt);

    // ---- BatchNorm -> h (pre-split) ----
    hipMemsetAsync(bnsums, 0, 2 * DD * 4, stream);
    bn_stats<<<800, 256, 0, stream>>>(x, bnsums);
    bn_apply<<<25000, 256, 0, stream>>>(x, bnsums, gamma, beta, h_hi, h_lo);

    // ---- degree / CSR (layer-invariant); dinv+starts zeroed in one memset ----
    hipMemsetAsync(dinv, 0, (size_t)KN * 4 + ((size_t)KN + 1) * 4, stream);
    deg_count<<<(KD * EE + 255) / 256, 256, 0, stream>>>(ei, ew, dinv, starts);
    dinv_kernel<<<(KN + 255) / 256, 256, 0, stream>>>(dinv);
    scan_blocks<<<SCAN_NB, 256, 0, stream>>>(starts, bsums);
    scan_sums<<<1, 1024, 0, stream>>>(bsums);
    scan_add<<<SCAN_NB, 256, 0, stream>>>(starts, bsums);
    csr_fill<<<(KD * EE + 255) / 256, 256, 0, stream>>>(ei, ew, dinv, starts, edata);

    const int MB64 = (NN + 63) / 64;     // 1563
    for (int l = 0; l < LL; ++l) {
        // xw(bf16) = h @ gcn_W[l] — BM=64 x BN=256, copy-only staging
        gemm_mfma<256, 1, true, false, 0><<<dim3(MB64, 1), 256, 0, stream>>>(
            nullptr, h_hi, h_lo, gcnWb + (size_t)l * DD * DD, nullptr,
            nullptr, xw, NN, DD, DD);
        gather_agg<<<(KN + 3) / 4, 256, 0, stream>>>(starts, edata, xw, xs);
        att_combine<<<MB64, 256, 0, stream>>>(
            xs, attWb + (size_t)l * KD * ATTD * DD,
            batt + (size_t)l * KD * ATTD, att_q + (size_t)l * KD * ATTD,
            gcn_b + l * DD, h_hi, h_lo);
    }

    // ---- projection head ----
    gemm_mfma<128, 0, true, true, 1><<<dim3(MB64, 1), 256, 0, stream>>>(
        nullptr, h_hi, h_lo, pW1b, pb1, p1tmp, nullptr, NN, DD, HH1);
    gemm_mfma<64, 0, false, true, 1><<<dim3(MB64, 1), 256, 0, stream>>>(
        p1tmp, nullptr, nullptr, pW2b, pb2, out, nullptr, NN, HH1, HH2);
}